// Round 3
// baseline (1619.091 us; speedup 1.0000x reference)
//
#include <hip/hip_runtime.h>
#include <math.h>

#define B_ 8
#define P_ 8192
#define N_ 65536
#define K_ 16
#define EPS_ 1e-5f

// ---------------------------------------------------------------------------
// KNN: brute force, one thread per query, candidate tiles staged in LDS.
// Distances computed with explicit _rn intrinsics (no FMA contraction) so they
// bitwise-match the numpy reference; strict-< insertion reproduces top_k's
// lower-index tie-break. Output neighbor SET therefore matches exactly (the
// final result is invariant to neighbor order: softmax/max commute with perms).
// Indices fit in ushort (N=65536) -> halves idx traffic and ws footprint.
// ---------------------------------------------------------------------------
__global__ __launch_bounds__(256) void knn_kernel(const float* __restrict__ vc,
                                                  unsigned short* __restrict__ idx_out,
                                                  float* __restrict__ d2_out) {
    const int q = blockIdx.x * 256 + threadIdx.x;   // global query id
    const int base = q & ~(P_ - 1);                 // batch base
    const float4 pq = ((const float4*)vc)[q];       // [batch, x, y, z]
    const float qx = pq.y, qy = pq.z, qz = pq.w;

    __shared__ __align__(16) float4 tile[1024];

    float bd[K_]; int bi[K_];
#pragma unroll
    for (int t = 0; t < K_; ++t) { bd[t] = __builtin_huge_valf(); bi[t] = 0; }

    for (int t0 = 0; t0 < P_; t0 += 1024) {
        __syncthreads();
        for (int i = threadIdx.x; i < 1024; i += 256)
            tile[i] = ((const float4*)vc)[base + t0 + i];
        __syncthreads();
#pragma unroll 4
        for (int j = 0; j < 1024; ++j) {
            float4 pc = tile[j];
            float dx = __fsub_rn(qx, pc.y);
            float dy = __fsub_rn(qy, pc.z);
            float dz = __fsub_rn(qz, pc.w);
            float d  = __fadd_rn(__fadd_rn(__fmul_rn(dx,dx), __fmul_rn(dy,dy)),
                                 __fmul_rn(dz,dz));
            if (d < bd[K_-1]) {
                int jg = base + t0 + j;
#pragma unroll
                for (int t = K_-1; t > 0; --t) {
                    bool gm = bd[t-1] > d;
                    bool gt = bd[t]   > d;
                    float sb = gm ? bd[t-1] : d;
                    int   si = gm ? bi[t-1] : jg;
                    if (gt) { bd[t] = sb; bi[t] = si; }
                }
                if (bd[0] > d) { bd[0] = d; bi[0] = jg; }
            }
        }
    }
#pragma unroll
    for (int t = 0; t < K_; ++t) {
        idx_out[q*K_ + t] = (unsigned short)bi[t];
        d2_out[q*K_ + t]  = bd[t];
    }
}

static __device__ inline double shfl_xor_dbl(double v, int mask) {
    long long b = __double_as_longlong(v);
    int lo = (int)(b & 0xffffffffLL);
    int hi = (int)(b >> 32);
    lo = __shfl_xor(lo, mask, 64);
    hi = __shfl_xor(hi, mask, 64);
    return __longlong_as_double(((long long)hi << 32) | (unsigned long long)(unsigned int)lo);
}

// ---------------------------------------------------------------------------
// EdgeConv. One "group" of COUT lanes handles one point n (lane = out channel).
// h[o,k] = (Wl-Wr)[o]·xi + Wr[o]·xj[k] + b[o]   (factored; halves FLOPs+LDS)
// PHA=true : per-channel sum/sumsq in FP64 (fp32 E[h^2]-mu^2 cancels badly).
// PHA=false: normalize with precomputed a,c; per-n attention + max-pool.
// Correctness-first: explicit __syncthreads() between all LDS stages
// (uniform trip counts, so block-wide barriers are legal).
// ---------------------------------------------------------------------------
template<int CIN, int COUT, bool PHA>
__global__ __launch_bounds__(256) void edge_kernel(
    const float* __restrict__ x,      // N x CIN
    const unsigned short* __restrict__ idx, // N x K
    const float* __restrict__ d2,     // N x K
    const float* __restrict__ W,      // COUT x 2CIN
    const float* __restrict__ bias,   // COUT
    const float* __restrict__ wk,     // COUT
    const float* __restrict__ wq,     // COUT
    const float* __restrict__ acoef,  // COUT (phase B)
    const float* __restrict__ ccoef,  // COUT (phase B)
    double* __restrict__ gsum,        // COUT (phase A)
    double* __restrict__ gsumsq,      // COUT (phase A)
    float* __restrict__ out,          // N x COUT (phase B)
    int niter)
{
    constexpr int LOGC = (COUT == 64) ? 6 : 5;
    constexpr int GPW  = 64 / COUT;        // groups per wave
    constexpr int GPB  = 4 * GPW;          // groups per block (256 threads)
    constexpr int C4   = CIN / 4;
    constexpr int SJ   = (K_ + 1) * CIN;   // K xj rows + xi row
    constexpr int HTS  = COUT + 1;         // padded transpose stride
    constexpr int HTN  = PHA ? 1 : (K_ * HTS);
    constexpr int PN   = PHA ? 1 : (K_ * K_);
    constexpr int KQN  = PHA ? 1 : (2 * K_);
    constexpr int SCN  = PHA ? 1 : K_;
    constexpr int PARTN= (!PHA && COUT == 64) ? 64 : 1;
    constexpr int WKQN = PHA ? 1 : (2 * COUT);

    const int tid  = threadIdx.x;
    const int wave = tid >> 6;
    const int lane = tid & 63;
    const int lo   = lane & (COUT - 1);    // channel o
    const int grp  = lane >> LOGC;         // group within wave
    const int gidx = wave * GPW + grp;     // group within block

    __shared__ __align__(16) float sj_s[GPB][SJ];
    __shared__ __align__(16) float hT_s[GPB][HTN];
    __shared__ __align__(16) float p_s[GPB][PN];
    __shared__ __align__(16) float kqv_s[GPB][KQN];
    __shared__ __align__(16) float rden_s[GPB][SCN];
    __shared__ __align__(16) float scal_s[GPB][SCN];
    __shared__ __align__(16) float part_s[GPB][PARTN];
    __shared__ __align__(16) float wkq_s[WKQN];

    // per-lane weight rows in registers
    float Wr[CIN], Ad[CIN];
#pragma unroll
    for (int c = 0; c < CIN; ++c) {
        float wl = W[lo * (2*CIN) + c];
        float wr = W[lo * (2*CIN) + CIN + c];
        Wr[c] = wr; Ad[c] = wl - wr;
    }
    const float b_s = bias[lo];

    float a_s = 0.f, c_s = 0.f;
    if constexpr (!PHA) {
        a_s = acoef[lo]; c_s = ccoef[lo];
        if (tid < COUT)            wkq_s[tid] = wk[tid];
        else if (tid < 2*COUT)     wkq_s[tid] = wq[tid - COUT];
    }
    __syncthreads();

    double lsum = 0.0, lsq = 0.0;
    const int g0      = blockIdx.x * GPB + gidx;
    const int gstride = gridDim.x * GPB;

    for (int it = 0; it < niter; ++it) {
        const int n = g0 + it * gstride;

        // ---- stage xj rows (k<K) and xi row (k==K) into LDS (float4) ----
        {
            const float4* xs  = (const float4*)x;
            float4*       sj4 = (float4*)sj_s[gidx];
            constexpr int TOT4 = (K_ + 1) * C4;
#pragma unroll
            for (int e0 = 0; e0 < TOT4; e0 += COUT) {
                int e = e0 + lo;
                if (e < TOT4) {
                    int r = e / C4;
                    int c = e - r * C4;
                    int row = (r < K_) ? (int)idx[n * K_ + r] : n;
                    sj4[e] = xs[row * C4 + c];
                }
            }
        }
        if constexpr (!PHA) {
            if (lo < K_) {
                // scale = 2*sigmoid(-dis), stable form (matches jax)
                float dis = sqrtf(d2[n * K_ + lo]);
                float e = __expf(-dis);
                scal_s[gidx][lo] = 2.0f * e / (1.0f + e);
            }
        }
        __syncthreads();   // staging -> compute

        const float* sj = sj_s[gidx];
        float t0 = b_s;
#pragma unroll
        for (int c = 0; c < C4; ++c) {
            float4 v = ((const float4*)(sj + K_ * CIN))[c];
            t0 = fmaf(Ad[4*c  ], v.x, t0);
            t0 = fmaf(Ad[4*c+1], v.y, t0);
            t0 = fmaf(Ad[4*c+2], v.z, t0);
            t0 = fmaf(Ad[4*c+3], v.w, t0);
        }
        float hn[K_];
#pragma unroll
        for (int k = 0; k < K_; ++k) {
            float acc = t0;
            const float4* xr = (const float4*)(sj + k * CIN);
#pragma unroll
            for (int c = 0; c < C4; ++c) {
                float4 v = xr[c];
                acc = fmaf(Wr[4*c  ], v.x, acc);
                acc = fmaf(Wr[4*c+1], v.y, acc);
                acc = fmaf(Wr[4*c+2], v.z, acc);
                acc = fmaf(Wr[4*c+3], v.w, acc);
            }
            float h = fmaxf(acc, 0.f);
            if constexpr (PHA) {
                double hd = (double)h;
                lsum += hd;
                lsq  = fma(hd, hd, lsq);
            } else {
                hn[k] = fmaf(a_s, h, c_s);
            }
        }

        if constexpr (!PHA) {
            // transpose to LDS (padded stride -> conflict-free columns)
            float* hT = hT_s[gidx];
#pragma unroll
            for (int k = 0; k < K_; ++k) hT[k * HTS + lo] = hn[k];
            __syncthreads();   // transpose -> Kv/Qv

            // Kv/Qv: lanes split roles over {K,Q} x channel-halves
            const int kk   = lo & 15;
            const int role = lo >> 4;
            float av = 0.f;
            const float* hrow = hT + kk * HTS;
            int obase; const float* wv;
            if constexpr (COUT == 64) { obase = (role & 1) * 32; wv = wkq_s + ((role >> 1) ? COUT : 0); }
            else                      { obase = 0;               wv = wkq_s + (role ? COUT : 0); }
#pragma unroll
            for (int j = 0; j < 32; ++j)
                av = fmaf(hrow[obase + j], wv[obase + j], av);
            if constexpr (COUT == 64) {
                part_s[gidx][lo] = av;
                __syncthreads();  // partials -> combine
                if (lo < 16)      kqv_s[gidx][lo] = part_s[gidx][lo]      + part_s[gidx][lo + 16]; // Kv
                else if (lo < 32) kqv_s[gidx][lo] = part_s[gidx][lo + 16] + part_s[gidx][lo + 32]; // Qv
            } else {
                kqv_s[gidx][lo] = av;   // [0,16)=Kv, [16,32)=Qv
            }
            __syncthreads();   // kqv -> softmax

            // softmax over k, per q (lanes lo<16); store unnormalized p + 1/den
            if (lo < K_) {
                const int q = lo;
                const float qv = kqv_s[gidx][K_ + q];
                float m = -__builtin_huge_valf();
#pragma unroll
                for (int k = 0; k < K_; ++k) m = fmaxf(m, kqv_s[gidx][k] * qv);
                float den = 0.f;
#pragma unroll
                for (int k = 0; k < K_; ++k) {
                    float e = __expf(kqv_s[gidx][k] * qv - m);
                    den += e;
                    p_s[gidx][k * K_ + q] = e;
                }
                rden_s[gidx][q] = 1.0f / den;
            }
            __syncthreads();   // softmax -> weighted sum

            // hout[o][q] = sum_k hn[k] * p[k][q]   (p broadcast as float4)
            float hq[K_];
#pragma unroll
            for (int q = 0; q < K_; ++q) hq[q] = 0.f;
#pragma unroll
            for (int k = 0; k < K_; ++k) {
                const float hnk = hn[k];
                const float4* p4 = (const float4*)(p_s[gidx] + k * K_);
#pragma unroll
                for (int j = 0; j < 4; ++j) {
                    float4 v = p4[j];
                    hq[4*j  ] = fmaf(hnk, v.x, hq[4*j  ]);
                    hq[4*j+1] = fmaf(hnk, v.y, hq[4*j+1]);
                    hq[4*j+2] = fmaf(hnk, v.z, hq[4*j+2]);
                    hq[4*j+3] = fmaf(hnk, v.w, hq[4*j+3]);
                }
            }
            // out[o] = max_q scale[q] * (hq[q] / den[q])
            float res = -__builtin_huge_valf();
#pragma unroll
            for (int j = 0; j < 4; ++j) {
                float4 sc = ((const float4*)scal_s[gidx])[j];
                float4 rd = ((const float4*)rden_s[gidx])[j];
                res = fmaxf(res, sc.x * (hq[4*j  ] * rd.x));
                res = fmaxf(res, sc.y * (hq[4*j+1] * rd.y));
                res = fmaxf(res, sc.z * (hq[4*j+2] * rd.z));
                res = fmaxf(res, sc.w * (hq[4*j+3] * rd.w));
            }
            out[n * COUT + lo] = res;
            __syncthreads();   // epilogue -> next-iter staging
        } else {
            __syncthreads();   // compute -> next-iter staging
        }
    }

    if constexpr (PHA) {
        if constexpr (COUT == 32) {
            lsum += shfl_xor_dbl(lsum, 32);
            lsq  += shfl_xor_dbl(lsq, 32);
        }
        __shared__ double redS[4][COUT];
        __shared__ double redQ[4][COUT];
        if (lane < COUT) { redS[wave][lane] = lsum; redQ[wave][lane] = lsq; }
        __syncthreads();
        if (tid < COUT) {
            double s  = redS[0][tid] + redS[1][tid] + redS[2][tid] + redS[3][tid];
            double qq = redQ[0][tid] + redQ[1][tid] + redQ[2][tid] + redQ[3][tid];
            atomicAdd(&gsum[tid], s);
            atomicAdd(&gsumsq[tid], qq);
        }
    }
}

// mu/var -> fused scale/shift:  hn = a*h + c   (all math in fp64)
__global__ void finalize_kernel(const double* __restrict__ gsum, const double* __restrict__ gsumsq,
                                const float* __restrict__ gamma, const float* __restrict__ beta,
                                float* __restrict__ a, float* __restrict__ c, int cout)
{
    int o = threadIdx.x;
    if (o < cout) {
        const double inv = 1.0 / ((double)N_ * (double)K_);
        double mu  = gsum[o] * inv;
        double var = gsumsq[o] * inv - mu * mu;
        double rs  = 1.0 / sqrt(var + (double)EPS_);
        double av  = rs * (double)gamma[o];
        a[o] = (float)av;
        c[o] = (float)((double)beta[o] - mu * av);
    }
}

__global__ __launch_bounds__(256) void copy_vc(const float4* __restrict__ src,
                                               float4* __restrict__ dst) {
    int i = blockIdx.x * 256 + threadIdx.x;
    dst[i] = src[i];
}

extern "C" void kernel_launch(void* const* d_in, const int* in_sizes, int n_in,
                              void* d_out, int out_size, void* d_ws, size_t ws_size,
                              hipStream_t stream)
{
    const float* pillar = (const float*)d_in[0];
    const float* vc     = (const float*)d_in[1];
    const float* W0  = (const float*)d_in[2];
    const float* b0  = (const float*)d_in[3];
    const float* g0  = (const float*)d_in[4];
    const float* be0 = (const float*)d_in[5];
    const float* wk0 = (const float*)d_in[6];
    const float* wq0 = (const float*)d_in[7];
    const float* W1  = (const float*)d_in[8];
    const float* b1  = (const float*)d_in[9];
    const float* g1  = (const float*)d_in[10];
    const float* be1 = (const float*)d_in[11];
    const float* wk1 = (const float*)d_in[12];
    const float* wq1 = (const float*)d_in[13];

    // ---- workspace layout: everything < 16 MiB, stats FIRST (ws_size-safe) --
    char* ws = (char*)d_ws;
    double* dsum = (double*)ws;                    // 256 doubles @ 0   (2 KB)
    double *s0 = dsum, *sq0 = dsum + 64, *s1 = dsum + 128, *sq1 = dsum + 192;
    float* coef = (float*)(ws + 4096);             // 256 floats @ 4 KB (1 KB)
    float *a0 = coef, *c0 = coef + 64, *a1 = coef + 128, *c1 = coef + 192;
    unsigned short* idx = (unsigned short*)(ws + 8192);       // N*K u16 (2 MB)
    float* d2  = (float*)(ws + 8192 + (size_t)N_*K_*2);       // N*K f32 (4 MB)
    float* x1  = (float*)(ws + 8192 + (size_t)N_*K_*6);       // N*32 f32 (8 MB)

    float* xout = (float*)d_out;                   // N*64
    float* vout = xout + (size_t)N_ * 64;          // N*4 (voxel_coords passthrough)

    hipMemsetAsync(dsum, 0, 2048, stream);
    knn_kernel<<<N_ / 256, 256, 0, stream>>>(vc, idx, d2);

    // layer 0: cin=4, cout=32
    edge_kernel<4,32,true ><<<1024, 256, 0, stream>>>(pillar, idx, d2, W0, b0, wk0, wq0,
                                                      nullptr, nullptr, s0, sq0, nullptr, 8);
    finalize_kernel<<<1, 64, 0, stream>>>(s0, sq0, g0, be0, a0, c0, 32);
    edge_kernel<4,32,false><<<1024, 256, 0, stream>>>(pillar, idx, d2, W0, b0, wk0, wq0,
                                                      a0, c0, nullptr, nullptr, x1, 8);

    // layer 1: cin=32, cout=64
    edge_kernel<32,64,true ><<<2048, 256, 0, stream>>>(x1, idx, d2, W1, b1, wk1, wq1,
                                                       nullptr, nullptr, s1, sq1, nullptr, 8);
    finalize_kernel<<<1, 64, 0, stream>>>(s1, sq1, g1, be1, a1, c1, 64);
    edge_kernel<32,64,false><<<2048, 256, 0, stream>>>(x1, idx, d2, W1, b1, wk1, wq1,
                                                       a1, c1, nullptr, nullptr, xout, 8);

    copy_vc<<<256, 256, 0, stream>>>((const float4*)vc, (float4*)vout);
}

// Round 4
// 1225.264 us; speedup vs baseline: 1.3214x; 1.3214x over previous
//
#include <hip/hip_runtime.h>
#include <math.h>

#define B_ 8
#define P_ 8192
#define N_ 65536
#define K_ 16
#define EPS_ 1e-5f
#define NBK 1024                 // x-buckets per batch
#define BSCALE 20.48f            // NBK / 50.0
#define RAD0 4.5f                // initial window radius (exactness guarded by expansion loop)

// ============================ binning ======================================
__global__ __launch_bounds__(256) void init_bins(int* counts, int* cursors,
                                                 int* xminI, int* xmaxI) {
    int i = blockIdx.x * 256 + threadIdx.x;   // 8192 entries
    counts[i] = 0; cursors[i] = 0;
    xminI[i] = 0x7F7FFFFF;                    // +FLT_MAX bits (x >= 0 -> int order == float order)
    xmaxI[i] = 0x80000000;                    // < any non-negative float's bits
}

__device__ __forceinline__ int bucket_of(float x) {
    int b = (int)(x * BSCALE);
    return b > (NBK - 1) ? (NBK - 1) : (b < 0 ? 0 : b);
}

__global__ __launch_bounds__(256) void count_kernel(const float* __restrict__ vc,
                                                    int* counts, int* xminI, int* xmaxI) {
    int q = blockIdx.x * 256 + threadIdx.x;
    float4 p = ((const float4*)vc)[q];        // [batch, x, y, z]
    int b = q >> 13;
    int bk = bucket_of(p.y);
    int e = b * NBK + bk;
    atomicAdd(&counts[e], 1);
    int xb = __float_as_int(p.y);
    atomicMin(&xminI[e], xb);
    atomicMax(&xmaxI[e], xb);
}

// per-batch: exclusive-sum of counts -> off; prefix-max of xmax -> xlub;
// suffix-min of xmin -> xglb. One block of 1024 threads per batch.
__global__ __launch_bounds__(1024) void scan_kernel(const int* __restrict__ counts,
                                                    const int* __restrict__ xminI,
                                                    const int* __restrict__ xmaxI,
                                                    int* off, float* xlub, float* xglb) {
    __shared__ int   smi[NBK];
    __shared__ float smf[NBK];
    int b = blockIdx.x, t = threadIdx.x;
    int e = b * NBK + t;

    // --- exclusive sum ---
    int c = counts[e];
    smi[t] = c; __syncthreads();
    for (int s = 1; s < NBK; s <<= 1) {
        int u = smi[t]; int v = (t >= s) ? smi[t - s] : 0;
        __syncthreads(); smi[t] = u + v; __syncthreads();
    }
    off[b * (NBK + 1) + t] = smi[t] - c;
    if (t == NBK - 1) off[b * (NBK + 1) + NBK] = smi[t];

    // --- prefix max of xmax (empty -> -1e30 sentinel) ---
    float mx = c ? __int_as_float(xmaxI[e]) : -1e30f;
    smf[t] = mx; __syncthreads();
    for (int s = 1; s < NBK; s <<= 1) {
        float u = smf[t]; float v = (t >= s) ? smf[t - s] : -1e30f;
        __syncthreads(); smf[t] = fmaxf(u, v); __syncthreads();
    }
    xlub[e] = smf[t];
    __syncthreads();

    // --- suffix min of xmin (reversed-index prefix min; empty -> +1e30) ---
    int r = NBK - 1 - t;
    int cr_ = counts[b * NBK + r];
    float mn = cr_ ? __int_as_float(xminI[b * NBK + r]) : 1e30f;
    smf[t] = mn; __syncthreads();
    for (int s = 1; s < NBK; s <<= 1) {
        float u = smf[t]; float v = (t >= s) ? smf[t - s] : 1e30f;
        __syncthreads(); smf[t] = fminf(u, v); __syncthreads();
    }
    xglb[b * NBK + r] = smf[t];
}

__global__ __launch_bounds__(256) void scatter_kernel(const float* __restrict__ vc,
                                                      const int* __restrict__ off,
                                                      int* cursors, float4* pos4s) {
    int q = blockIdx.x * 256 + threadIdx.x;
    float4 p = ((const float4*)vc)[q];
    int b = q >> 13;
    int bk = bucket_of(p.y);
    int slot = off[b * (NBK + 1) + bk] + atomicAdd(&cursors[b * NBK + bk], 1);
    pos4s[(b << 13) + slot] = make_float4(p.y, p.z, p.w, __int_as_float(q));
}

// ============================ knn (pruned, exact) ==========================
// Thread = one sorted slot. Wave lanes are 64 consecutive sorted points of one
// batch (64 | 8192 -> no straddle) -> wave-uniform candidate windows, uniform
// (broadcast) global loads, no LDS, no barriers.
// Pass 1: 16 smallest distances via min/max network -> tau = exact 16th value.
// Pass 2: rescan (window widened with <=), collect (d,origIdx) for d <= tau,
// drop lex-largest extras -> exact top_k semantics incl. lowest-index ties.
__global__ __launch_bounds__(256) void knn2_kernel(const float4* __restrict__ pos4s,
                                                   const int* __restrict__ off,
                                                   const float* __restrict__ xlub,
                                                   const float* __restrict__ xglb,
                                                   unsigned short* __restrict__ idx_out,
                                                   float* __restrict__ d2_out) {
    const int s = blockIdx.x * 256 + threadIdx.x;
    const int b = s >> 13;
    const float4 me = pos4s[s];
    const float qx = me.x, qy = me.y, qz = me.z;
    const int q = __float_as_int(me.w);
    const float4* cp = pos4s + ((size_t)b << 13);
    const int*   offb = off + b * (NBK + 1);
    const float* xl = xlub + (b << 10);
    const float* xg = xglb + (b << 10);

    const float xq0  = __shfl(qx, 0);
    const float xq63 = __shfl(qx, 63);
    int bLi = bucket_of(fmaxf(xq0 - RAD0, 0.f));
    int bRi = bucket_of(xq63 + RAD0);
    bLi = __builtin_amdgcn_readfirstlane(bLi);
    bRi = __builtin_amdgcn_readfirstlane(bRi);

    float bd[K_];
#pragma unroll
    for (int t = 0; t < K_; ++t) bd[t] = __builtin_huge_valf();
    float bd15 = __builtin_huge_valf();

#define DIST(c, d)                                                          \
    float dx = __fsub_rn(qx, (c).x);                                        \
    float dy = __fsub_rn(qy, (c).y);                                        \
    float dz = __fsub_rn(qz, (c).z);                                        \
    float d  = __fadd_rn(__fadd_rn(__fmul_rn(dx,dx), __fmul_rn(dy,dy)),     \
                         __fmul_rn(dz,dz));

#define P1BODY(j) {                                                         \
        float4 c = cp[j];                                                   \
        DIST(c, d)                                                          \
        if (d < bd15) {                                                     \
            _Pragma("unroll")                                               \
            for (int t = K_-1; t > 0; --t)                                  \
                bd[t] = fminf(bd[t], fmaxf(bd[t-1], d));                    \
            bd[0] = fminf(bd[0], d);                                        \
            bd15 = bd[K_-1];                                                \
        }                                                                   \
    }

    // pass 1: initial linear window
    {
        int jL = offb[bLi], jR = offb[bRi + 1];
        for (int j = jL; j < jR; ++j) P1BODY(j)
    }
    // pass 1: exact expansion
    int clo = bLi, chi = bRi;
    int cl = bLi - 1, cr = bRi + 1;
    for (;;) {
        bool nL = false, nR = false;
        if (cl >= 0)  { float t = __fsub_rn(qx, xl[cl]); nL = __fmul_rn(t,t) < bd15; }
        if (cr < NBK) { float t = __fsub_rn(xg[cr], qx); nR = __fmul_rn(t,t) < bd15; }
        unsigned long long mL = __ballot(nL), mR = __ballot(nR);
        if (!mL && !mR) break;
        if (mL) { int j0 = offb[cl], j1 = offb[cl+1];
                  for (int j = j0; j < j1; ++j) P1BODY(j)
                  clo = cl; --cl; }
        if (mR) { int j0 = offb[cr], j1 = offb[cr+1];
                  for (int j = j0; j < j1; ++j) P1BODY(j)
                  chi = cr; ++cr; }
    }

    // pass 2: collect (d, idx) with d <= tau
    const float tau = bd15;
    float dc[18]; int ic[18]; int cnt = 0;
#pragma unroll
    for (int t = 0; t < 18; ++t) { dc[t] = 0.f; ic[t] = 0; }

#define P2BODY(j) {                                                         \
        float4 c = cp[j];                                                   \
        DIST(c, d)                                                          \
        if (d <= tau) {                                                     \
            int cidx = __float_as_int(c.w);                                 \
            _Pragma("unroll")                                               \
            for (int t = 0; t < 18; ++t)                                    \
                if (cnt == t) { dc[t] = d; ic[t] = cidx; }                  \
            if (cnt < 18) ++cnt;                                            \
        }                                                                   \
    }

    {
        int jL = offb[clo], jR = offb[chi + 1];
        for (int j = jL; j < jR; ++j) P2BODY(j)
    }
    cl = clo - 1; cr = chi + 1;
    for (;;) {
        bool nL = false, nR = false;
        if (cl >= 0)  { float t = __fsub_rn(qx, xl[cl]); nL = __fmul_rn(t,t) <= tau; }
        if (cr < NBK) { float t = __fsub_rn(xg[cr], qx); nR = __fmul_rn(t,t) <= tau; }
        unsigned long long mL = __ballot(nL), mR = __ballot(nR);
        if (!mL && !mR) break;
        if (mL) { int j0 = offb[cl], j1 = offb[cl+1];
                  for (int j = j0; j < j1; ++j) P2BODY(j)
                  --cl; }
        if (mR) { int j0 = offb[cr], j1 = offb[cr+1];
                  for (int j = j0; j < j1; ++j) P2BODY(j)
                  ++cr; }
    }

    // drop lex-largest extras (boundary ties; rare)
    while (cnt > 16) {
        float md = dc[0]; int mi = ic[0]; int mt = 0;
#pragma unroll
        for (int t = 1; t < 18; ++t) {
            bool valid = (t < cnt);
            bool g = valid && ((dc[t] > md) || (dc[t] == md && ic[t] > mi));
            if (g) { md = dc[t]; mi = ic[t]; mt = t; }
        }
        float ld = 0.f; int li = 0;
#pragma unroll
        for (int t = 0; t < 18; ++t) if (t == cnt - 1) { ld = dc[t]; li = ic[t]; }
#pragma unroll
        for (int t = 0; t < 18; ++t) if (t == mt) { dc[t] = ld; ic[t] = li; }
        --cnt;
    }

#pragma unroll
    for (int t = 0; t < K_; ++t) {
        idx_out[(size_t)q * K_ + t] = (unsigned short)ic[t];
        d2_out[(size_t)q * K_ + t]  = dc[t];
    }
#undef P1BODY
#undef P2BODY
#undef DIST
}

// ============================ edgeconv (unchanged from R3) =================
static __device__ inline double shfl_xor_dbl(double v, int mask) {
    long long b = __double_as_longlong(v);
    int lo = (int)(b & 0xffffffffLL);
    int hi = (int)(b >> 32);
    lo = __shfl_xor(lo, mask, 64);
    hi = __shfl_xor(hi, mask, 64);
    return __longlong_as_double(((long long)hi << 32) | (unsigned long long)(unsigned int)lo);
}

template<int CIN, int COUT, bool PHA>
__global__ __launch_bounds__(256) void edge_kernel(
    const float* __restrict__ x,
    const unsigned short* __restrict__ idx,
    const float* __restrict__ d2,
    const float* __restrict__ W,
    const float* __restrict__ bias,
    const float* __restrict__ wk,
    const float* __restrict__ wq,
    const float* __restrict__ acoef,
    const float* __restrict__ ccoef,
    double* __restrict__ gsum,
    double* __restrict__ gsumsq,
    float* __restrict__ out,
    int niter)
{
    constexpr int LOGC = (COUT == 64) ? 6 : 5;
    constexpr int GPW  = 64 / COUT;
    constexpr int GPB  = 4 * GPW;
    constexpr int C4   = CIN / 4;
    constexpr int SJ   = (K_ + 1) * CIN;
    constexpr int HTS  = COUT + 1;
    constexpr int HTN  = PHA ? 1 : (K_ * HTS);
    constexpr int PN   = PHA ? 1 : (K_ * K_);
    constexpr int KQN  = PHA ? 1 : (2 * K_);
    constexpr int SCN  = PHA ? 1 : K_;
    constexpr int PARTN= (!PHA && COUT == 64) ? 64 : 1;
    constexpr int WKQN = PHA ? 1 : (2 * COUT);

    const int tid  = threadIdx.x;
    const int wave = tid >> 6;
    const int lane = tid & 63;
    const int lo   = lane & (COUT - 1);
    const int grp  = lane >> LOGC;
    const int gidx = wave * GPW + grp;

    __shared__ __align__(16) float sj_s[GPB][SJ];
    __shared__ __align__(16) float hT_s[GPB][HTN];
    __shared__ __align__(16) float p_s[GPB][PN];
    __shared__ __align__(16) float kqv_s[GPB][KQN];
    __shared__ __align__(16) float rden_s[GPB][SCN];
    __shared__ __align__(16) float scal_s[GPB][SCN];
    __shared__ __align__(16) float part_s[GPB][PARTN];
    __shared__ __align__(16) float wkq_s[WKQN];

    float Wr[CIN], Ad[CIN];
#pragma unroll
    for (int c = 0; c < CIN; ++c) {
        float wl = W[lo * (2*CIN) + c];
        float wr = W[lo * (2*CIN) + CIN + c];
        Wr[c] = wr; Ad[c] = wl - wr;
    }
    const float b_s = bias[lo];

    float a_s = 0.f, c_s = 0.f;
    if constexpr (!PHA) {
        a_s = acoef[lo]; c_s = ccoef[lo];
        if (tid < COUT)            wkq_s[tid] = wk[tid];
        else if (tid < 2*COUT)     wkq_s[tid] = wq[tid - COUT];
    }
    __syncthreads();

    double lsum = 0.0, lsq = 0.0;
    const int g0      = blockIdx.x * GPB + gidx;
    const int gstride = gridDim.x * GPB;

    for (int it = 0; it < niter; ++it) {
        const int n = g0 + it * gstride;

        {
            const float4* xs  = (const float4*)x;
            float4*       sj4 = (float4*)sj_s[gidx];
            constexpr int TOT4 = (K_ + 1) * C4;
#pragma unroll
            for (int e0 = 0; e0 < TOT4; e0 += COUT) {
                int e = e0 + lo;
                if (e < TOT4) {
                    int r = e / C4;
                    int c = e - r * C4;
                    int row = (r < K_) ? (int)idx[n * K_ + r] : n;
                    sj4[e] = xs[row * C4 + c];
                }
            }
        }
        if constexpr (!PHA) {
            if (lo < K_) {
                float dis = sqrtf(d2[n * K_ + lo]);
                float e = __expf(-dis);
                scal_s[gidx][lo] = 2.0f * e / (1.0f + e);
            }
        }
        __syncthreads();

        const float* sj = sj_s[gidx];
        float t0 = b_s;
#pragma unroll
        for (int c = 0; c < C4; ++c) {
            float4 v = ((const float4*)(sj + K_ * CIN))[c];
            t0 = fmaf(Ad[4*c  ], v.x, t0);
            t0 = fmaf(Ad[4*c+1], v.y, t0);
            t0 = fmaf(Ad[4*c+2], v.z, t0);
            t0 = fmaf(Ad[4*c+3], v.w, t0);
        }
        float hn[K_];
#pragma unroll
        for (int k = 0; k < K_; ++k) {
            float acc = t0;
            const float4* xr = (const float4*)(sj + k * CIN);
#pragma unroll
            for (int c = 0; c < C4; ++c) {
                float4 v = xr[c];
                acc = fmaf(Wr[4*c  ], v.x, acc);
                acc = fmaf(Wr[4*c+1], v.y, acc);
                acc = fmaf(Wr[4*c+2], v.z, acc);
                acc = fmaf(Wr[4*c+3], v.w, acc);
            }
            float h = fmaxf(acc, 0.f);
            if constexpr (PHA) {
                double hd = (double)h;
                lsum += hd;
                lsq  = fma(hd, hd, lsq);
            } else {
                hn[k] = fmaf(a_s, h, c_s);
            }
        }

        if constexpr (!PHA) {
            float* hT = hT_s[gidx];
#pragma unroll
            for (int k = 0; k < K_; ++k) hT[k * HTS + lo] = hn[k];
            __syncthreads();

            const int kk   = lo & 15;
            const int role = lo >> 4;
            float av = 0.f;
            const float* hrow = hT + kk * HTS;
            int obase; const float* wv;
            if constexpr (COUT == 64) { obase = (role & 1) * 32; wv = wkq_s + ((role >> 1) ? COUT : 0); }
            else                      { obase = 0;               wv = wkq_s + (role ? COUT : 0); }
#pragma unroll
            for (int j = 0; j < 32; ++j)
                av = fmaf(hrow[obase + j], wv[obase + j], av);
            if constexpr (COUT == 64) {
                part_s[gidx][lo] = av;
                __syncthreads();
                if (lo < 16)      kqv_s[gidx][lo] = part_s[gidx][lo]      + part_s[gidx][lo + 16];
                else if (lo < 32) kqv_s[gidx][lo] = part_s[gidx][lo + 16] + part_s[gidx][lo + 32];
            } else {
                kqv_s[gidx][lo] = av;
            }
            __syncthreads();

            if (lo < K_) {
                const int qq = lo;
                const float qv = kqv_s[gidx][K_ + qq];
                float m = -__builtin_huge_valf();
#pragma unroll
                for (int k = 0; k < K_; ++k) m = fmaxf(m, kqv_s[gidx][k] * qv);
                float den = 0.f;
#pragma unroll
                for (int k = 0; k < K_; ++k) {
                    float e = __expf(kqv_s[gidx][k] * qv - m);
                    den += e;
                    p_s[gidx][k * K_ + qq] = e;
                }
                rden_s[gidx][qq] = 1.0f / den;
            }
            __syncthreads();

            float hq[K_];
#pragma unroll
            for (int qq = 0; qq < K_; ++qq) hq[qq] = 0.f;
#pragma unroll
            for (int k = 0; k < K_; ++k) {
                const float hnk = hn[k];
                const float4* p4 = (const float4*)(p_s[gidx] + k * K_);
#pragma unroll
                for (int j = 0; j < 4; ++j) {
                    float4 v = p4[j];
                    hq[4*j  ] = fmaf(hnk, v.x, hq[4*j  ]);
                    hq[4*j+1] = fmaf(hnk, v.y, hq[4*j+1]);
                    hq[4*j+2] = fmaf(hnk, v.z, hq[4*j+2]);
                    hq[4*j+3] = fmaf(hnk, v.w, hq[4*j+3]);
                }
            }
            float res = -__builtin_huge_valf();
#pragma unroll
            for (int j = 0; j < 4; ++j) {
                float4 sc = ((const float4*)scal_s[gidx])[j];
                float4 rd = ((const float4*)rden_s[gidx])[j];
                res = fmaxf(res, sc.x * (hq[4*j  ] * rd.x));
                res = fmaxf(res, sc.y * (hq[4*j+1] * rd.y));
                res = fmaxf(res, sc.z * (hq[4*j+2] * rd.z));
                res = fmaxf(res, sc.w * (hq[4*j+3] * rd.w));
            }
            out[n * COUT + lo] = res;
            __syncthreads();
        } else {
            __syncthreads();
        }
    }

    if constexpr (PHA) {
        if constexpr (COUT == 32) {
            lsum += shfl_xor_dbl(lsum, 32);
            lsq  += shfl_xor_dbl(lsq, 32);
        }
        __shared__ double redS[4][COUT];
        __shared__ double redQ[4][COUT];
        if (lane < COUT) { redS[wave][lane] = lsum; redQ[wave][lane] = lsq; }
        __syncthreads();
        if (tid < COUT) {
            double ss = redS[0][tid] + redS[1][tid] + redS[2][tid] + redS[3][tid];
            double qq = redQ[0][tid] + redQ[1][tid] + redQ[2][tid] + redQ[3][tid];
            atomicAdd(&gsum[tid], ss);
            atomicAdd(&gsumsq[tid], qq);
        }
    }
}

__global__ void finalize_kernel(const double* __restrict__ gsum, const double* __restrict__ gsumsq,
                                const float* __restrict__ gamma, const float* __restrict__ beta,
                                float* __restrict__ a, float* __restrict__ c, int cout)
{
    int o = threadIdx.x;
    if (o < cout) {
        const double inv = 1.0 / ((double)N_ * (double)K_);
        double mu  = gsum[o] * inv;
        double var = gsumsq[o] * inv - mu * mu;
        double rs  = 1.0 / sqrt(var + (double)EPS_);
        double av  = rs * (double)gamma[o];
        a[o] = (float)av;
        c[o] = (float)((double)beta[o] - mu * av);
    }
}

__global__ __launch_bounds__(256) void copy_vc(const float4* __restrict__ src,
                                               float4* __restrict__ dst) {
    int i = blockIdx.x * 256 + threadIdx.x;
    dst[i] = src[i];
}

extern "C" void kernel_launch(void* const* d_in, const int* in_sizes, int n_in,
                              void* d_out, int out_size, void* d_ws, size_t ws_size,
                              hipStream_t stream)
{
    const float* pillar = (const float*)d_in[0];
    const float* vc     = (const float*)d_in[1];
    const float* W0  = (const float*)d_in[2];
    const float* b0  = (const float*)d_in[3];
    const float* g0  = (const float*)d_in[4];
    const float* be0 = (const float*)d_in[5];
    const float* wk0 = (const float*)d_in[6];
    const float* wq0 = (const float*)d_in[7];
    const float* W1  = (const float*)d_in[8];
    const float* b1  = (const float*)d_in[9];
    const float* g1  = (const float*)d_in[10];
    const float* be1 = (const float*)d_in[11];
    const float* wk1 = (const float*)d_in[12];
    const float* wq1 = (const float*)d_in[13];

    // ---- workspace (< 16 MiB total) ----
    char* ws = (char*)d_ws;
    double* dsum = (double*)ws;                              // 2 KB @ 0
    double *s0 = dsum, *sq0 = dsum + 64, *s1 = dsum + 128, *sq1 = dsum + 192;
    float* coef = (float*)(ws + 4096);                       // 1 KB @ 4K
    float *a0 = coef, *c0 = coef + 64, *a1 = coef + 128, *c1 = coef + 192;
    unsigned short* idx = (unsigned short*)(ws + 8192);      // 2 MB
    float* d2  = (float*)(ws + 8192 + (size_t)N_*K_*2);      // 4 MB
    float* x1  = (float*)(ws + 8192 + (size_t)N_*K_*6);      // 8 MB
    size_t base2 = 8192 + (size_t)N_*K_*6 + (size_t)N_*32*4; // = 14 MB + 8 KB
    float4* pos4s = (float4*)(ws + base2);                   // 1 MB
    int* counts   = (int*)(ws + base2 + (1u<<20));           // 32 KB
    int* cursors  = counts + B_*NBK;                         // 32 KB
    int* off      = cursors + B_*NBK;                        // 8*1025*4
    int* xminI    = off + B_*(NBK+1);                        // 32 KB
    int* xmaxI    = xminI + B_*NBK;                          // 32 KB
    float* xlub   = (float*)(xmaxI + B_*NBK);                // 32 KB
    float* xglb   = xlub + B_*NBK;                           // 32 KB

    float* xout = (float*)d_out;
    float* vout = xout + (size_t)N_ * 64;

    hipMemsetAsync(dsum, 0, 2048, stream);
    init_bins<<<B_*NBK/256, 256, 0, stream>>>(counts, cursors, xminI, xmaxI);
    count_kernel<<<N_/256, 256, 0, stream>>>(vc, counts, xminI, xmaxI);
    scan_kernel<<<B_, NBK, 0, stream>>>(counts, xminI, xmaxI, off, xlub, xglb);
    scatter_kernel<<<N_/256, 256, 0, stream>>>(vc, off, cursors, pos4s);
    knn2_kernel<<<N_/256, 256, 0, stream>>>(pos4s, off, xlub, xglb, idx, d2);

    edge_kernel<4,32,true ><<<1024, 256, 0, stream>>>(pillar, idx, d2, W0, b0, wk0, wq0,
                                                      nullptr, nullptr, s0, sq0, nullptr, 8);
    finalize_kernel<<<1, 64, 0, stream>>>(s0, sq0, g0, be0, a0, c0, 32);
    edge_kernel<4,32,false><<<1024, 256, 0, stream>>>(pillar, idx, d2, W0, b0, wk0, wq0,
                                                      a0, c0, nullptr, nullptr, x1, 8);

    edge_kernel<32,64,true ><<<2048, 256, 0, stream>>>(x1, idx, d2, W1, b1, wk1, wq1,
                                                       nullptr, nullptr, s1, sq1, nullptr, 8);
    finalize_kernel<<<1, 64, 0, stream>>>(s1, sq1, g1, be1, a1, c1, 64);
    edge_kernel<32,64,false><<<2048, 256, 0, stream>>>(x1, idx, d2, W1, b1, wk1, wq1,
                                                       a1, c1, nullptr, nullptr, xout, 8);

    copy_vc<<<256, 256, 0, stream>>>((const float4*)vc, (float4*)vout);
}

// Round 5
// 959.576 us; speedup vs baseline: 1.6873x; 1.2769x over previous
//
#include <hip/hip_runtime.h>
#include <math.h>

#define B_ 8
#define P_ 8192
#define N_ 65536
#define K_ 16
#define EPS_ 1e-5f
#define NBK 1024                 // x-buckets per batch
#define BSCALE 20.48f            // NBK / 50.0

// ============================ binning ======================================
__global__ __launch_bounds__(256) void init_bins(int* counts, int* cursors,
                                                 int* xminI, int* xmaxI) {
    int i = blockIdx.x * 256 + threadIdx.x;   // 8192 entries
    counts[i] = 0; cursors[i] = 0;
    xminI[i] = 0x7F7FFFFF;                    // +FLT_MAX bits (x >= 0 -> int order == float order)
    xmaxI[i] = 0x80000000;                    // < any non-negative float's bits
}

__device__ __forceinline__ int bucket_of(float x) {
    int b = (int)(x * BSCALE);
    return b > (NBK - 1) ? (NBK - 1) : (b < 0 ? 0 : b);
}

__global__ __launch_bounds__(256) void count_kernel(const float* __restrict__ vc,
                                                    int* counts, int* xminI, int* xmaxI) {
    int q = blockIdx.x * 256 + threadIdx.x;
    float4 p = ((const float4*)vc)[q];        // [batch, x, y, z]
    int b = q >> 13;
    int bk = bucket_of(p.y);
    int e = b * NBK + bk;
    atomicAdd(&counts[e], 1);
    int xb = __float_as_int(p.y);
    atomicMin(&xminI[e], xb);
    atomicMax(&xmaxI[e], xb);
}

// per-batch: exclusive-sum of counts -> off; prefix-max of xmax -> xlub;
// suffix-min of xmin -> xglb. One block of 1024 threads per batch.
__global__ __launch_bounds__(1024) void scan_kernel(const int* __restrict__ counts,
                                                    const int* __restrict__ xminI,
                                                    const int* __restrict__ xmaxI,
                                                    int* off, float* xlub, float* xglb) {
    __shared__ int   smi[NBK];
    __shared__ float smf[NBK];
    int b = blockIdx.x, t = threadIdx.x;
    int e = b * NBK + t;

    int c = counts[e];
    smi[t] = c; __syncthreads();
    for (int s = 1; s < NBK; s <<= 1) {
        int u = smi[t]; int v = (t >= s) ? smi[t - s] : 0;
        __syncthreads(); smi[t] = u + v; __syncthreads();
    }
    off[b * (NBK + 1) + t] = smi[t] - c;
    if (t == NBK - 1) off[b * (NBK + 1) + NBK] = smi[t];

    float mx = c ? __int_as_float(xmaxI[e]) : -1e30f;
    smf[t] = mx; __syncthreads();
    for (int s = 1; s < NBK; s <<= 1) {
        float u = smf[t]; float v = (t >= s) ? smf[t - s] : -1e30f;
        __syncthreads(); smf[t] = fmaxf(u, v); __syncthreads();
    }
    xlub[e] = smf[t];
    __syncthreads();

    int r = NBK - 1 - t;
    int cr_ = counts[b * NBK + r];
    float mn = cr_ ? __int_as_float(xminI[b * NBK + r]) : 1e30f;
    smf[t] = mn; __syncthreads();
    for (int s = 1; s < NBK; s <<= 1) {
        float u = smf[t]; float v = (t >= s) ? smf[t - s] : 1e30f;
        __syncthreads(); smf[t] = fminf(u, v); __syncthreads();
    }
    xglb[b * NBK + r] = smf[t];
}

__global__ __launch_bounds__(256) void scatter_kernel(const float* __restrict__ vc,
                                                      const int* __restrict__ off,
                                                      int* cursors, float4* pos4s) {
    int q = blockIdx.x * 256 + threadIdx.x;
    float4 p = ((const float4*)vc)[q];
    int b = q >> 13;
    int bk = bucket_of(p.y);
    int slot = off[b * (NBK + 1) + bk] + atomicAdd(&cursors[b * NBK + bk], 1);
    pos4s[(b << 13) + slot] = make_float4(p.y, p.z, p.w, __int_as_float(q));
}

// ============================ knn (block-cooperative, exact) ===============
// Block = 256 consecutive x-sorted slots of one batch. Candidate tiles of 256
// staged cooperatively (coalesced global -> LDS), consumed via broadcast
// ds_read. Center-outward tile walk with exact per-bucket x-bound stops
// (conservative under _rn monotonicity). Pass 1: distance-only top-16 via
// min/max network -> tau. Pass 2: collect (d,idx) with d <= tau into per-
// thread LDS buffer; drop lex-largest extras -> exact top_k tie semantics.
__global__ __launch_bounds__(256) void knn3_kernel(const float4* __restrict__ pos4s,
                                                   const float* __restrict__ xlub,
                                                   const float* __restrict__ xglb,
                                                   unsigned short* __restrict__ idx_out,
                                                   float* __restrict__ d2_out) {
    const int tid   = threadIdx.x;
    const int bb    = blockIdx.x >> 5;            // batch (32 blocks/batch)
    const int bbase = bb << 13;
    const int home0 = bbase + ((blockIdx.x & 31) << 8);
    const float4 me = pos4s[home0 + tid];
    const float qx = me.x, qy = me.y, qz = me.z;
    const int q = __float_as_int(me.w);
    const float* xl = xlub + (bb << 10);
    const float* xg = xglb + (bb << 10);

    __shared__ __align__(16) float4 tile[256];    // 4 KB
    __shared__ float2 hb[256 * 19];               // 38 KB hit buffer
    __shared__ int sflags[2];

    float bd[K_];
#pragma unroll
    for (int t = 0; t < K_; ++t) bd[t] = __builtin_huge_valf();
    float bd15 = __builtin_huge_valf();

#define DIST_(c)                                                            \
    float dx = __fsub_rn(qx, (c).x);                                        \
    float dy = __fsub_rn(qy, (c).y);                                        \
    float dz = __fsub_rn(qz, (c).z);                                        \
    float d  = __fadd_rn(__fadd_rn(__fmul_rn(dx,dx), __fmul_rn(dy,dy)),     \
                         __fmul_rn(dz,dz));

#define SCAN_P1(base, cntT) {                                               \
    __syncthreads();                                                        \
    if (tid < (cntT)) tile[tid] = pos4s[(base) + tid];                      \
    __syncthreads();                                                        \
    _Pragma("unroll 4")                                                     \
    for (int j = 0; j < (cntT); ++j) {                                      \
        float4 c = tile[j];                                                 \
        DIST_(c)                                                            \
        if (d < bd15) {                                                     \
            _Pragma("unroll")                                               \
            for (int t = K_-1; t > 0; --t)                                  \
                bd[t] = fminf(bd[t], fmaxf(bd[t-1], d));                    \
            bd[0] = fminf(bd[0], d);                                        \
            bd15 = bd[K_-1];                                                \
        }                                                                   \
    } }

    // ---- pass 1: home tile, then center-outward expansion ----
    SCAN_P1(home0, 256)
    int sL = home0, sR = home0 + 256;
    for (;;) {
        bool needL = false, needR = false;
        if (sL > bbase) {
            float xb = xl[bucket_of(pos4s[sL - 1].x)];   // ub on x of slots < sL
            float t = __fsub_rn(qx, xb);
            needL = __fmul_rn(t, t) < bd15;
        }
        if (sR < bbase + P_) {
            float xb = xg[bucket_of(pos4s[sR].x)];       // lb on x of slots >= sR
            float t = __fsub_rn(xb, qx);
            needR = __fmul_rn(t, t) < bd15;
        }
        if (tid == 0) { sflags[0] = 0; sflags[1] = 0; }
        __syncthreads();
        if (needL) sflags[0] = 1;
        if (needR) sflags[1] = 1;
        __syncthreads();
        int aL = sflags[0], aR = sflags[1];
        if (!aL && !aR) break;
        if (aL) { int c_ = min(256, sL - bbase);       SCAN_P1(sL - c_, c_) sL -= c_; }
        if (aR) { int c_ = min(256, bbase + P_ - sR);  SCAN_P1(sR, c_)      sR += c_; }
    }

    // ---- pass 2: collect (d, idx) with d <= tau ----
    const float tau = bd15;
    int cnt = 0;
    const int hbase = tid * 19;

#define SCAN_P2(base, cntT) {                                               \
    __syncthreads();                                                        \
    if (tid < (cntT)) tile[tid] = pos4s[(base) + tid];                      \
    __syncthreads();                                                        \
    _Pragma("unroll 4")                                                     \
    for (int j = 0; j < (cntT); ++j) {                                      \
        float4 c = tile[j];                                                 \
        DIST_(c)                                                            \
        if (d <= tau && cnt < 19) {                                         \
            hb[hbase + cnt] = make_float2(d, c.w);                          \
            ++cnt;                                                          \
        }                                                                   \
    } }

    SCAN_P2(home0, 256)
    sL = home0; sR = home0 + 256;
    for (;;) {
        bool needL = false, needR = false;
        if (sL > bbase) {
            float xb = xl[bucket_of(pos4s[sL - 1].x)];
            float t = __fsub_rn(qx, xb);
            needL = __fmul_rn(t, t) <= tau;
        }
        if (sR < bbase + P_) {
            float xb = xg[bucket_of(pos4s[sR].x)];
            float t = __fsub_rn(xb, qx);
            needR = __fmul_rn(t, t) <= tau;
        }
        if (tid == 0) { sflags[0] = 0; sflags[1] = 0; }
        __syncthreads();
        if (needL) sflags[0] = 1;
        if (needR) sflags[1] = 1;
        __syncthreads();
        int aL = sflags[0], aR = sflags[1];
        if (!aL && !aR) break;
        if (aL) { int c_ = min(256, sL - bbase);       SCAN_P2(sL - c_, c_) sL -= c_; }
        if (aR) { int c_ = min(256, bbase + P_ - sR);  SCAN_P2(sR, c_)      sR += c_; }
    }

    // ---- readback + drop lex-largest extras (ties; cnt>16 is rare) ----
    float dc[19]; int ic[19];
#pragma unroll
    for (int t = 0; t < 19; ++t) {
        float2 v = hb[hbase + t];
        dc[t] = v.x; ic[t] = __float_as_int(v.y);
    }
    while (cnt > 16) {
        float md = dc[0]; int mi = ic[0]; int mt = 0;
#pragma unroll
        for (int t = 1; t < 19; ++t) {
            bool valid = (t < cnt);
            bool g = valid && ((dc[t] > md) || (dc[t] == md && ic[t] > mi));
            if (g) { md = dc[t]; mi = ic[t]; mt = t; }
        }
        float ld = 0.f; int li = 0;
#pragma unroll
        for (int t = 0; t < 19; ++t) if (t == cnt - 1) { ld = dc[t]; li = ic[t]; }
#pragma unroll
        for (int t = 0; t < 19; ++t) if (t == mt) { dc[t] = ld; ic[t] = li; }
        --cnt;
    }

#pragma unroll
    for (int t = 0; t < K_; ++t) {
        idx_out[(size_t)q * K_ + t] = (unsigned short)ic[t];
        d2_out[(size_t)q * K_ + t]  = dc[t];
    }
#undef SCAN_P1
#undef SCAN_P2
#undef DIST_
}

// ============================ edgeconv (unchanged) =========================
static __device__ inline double shfl_xor_dbl(double v, int mask) {
    long long b = __double_as_longlong(v);
    int lo = (int)(b & 0xffffffffLL);
    int hi = (int)(b >> 32);
    lo = __shfl_xor(lo, mask, 64);
    hi = __shfl_xor(hi, mask, 64);
    return __longlong_as_double(((long long)hi << 32) | (unsigned long long)(unsigned int)lo);
}

template<int CIN, int COUT, bool PHA>
__global__ __launch_bounds__(256) void edge_kernel(
    const float* __restrict__ x,
    const unsigned short* __restrict__ idx,
    const float* __restrict__ d2,
    const float* __restrict__ W,
    const float* __restrict__ bias,
    const float* __restrict__ wk,
    const float* __restrict__ wq,
    const float* __restrict__ acoef,
    const float* __restrict__ ccoef,
    double* __restrict__ gsum,
    double* __restrict__ gsumsq,
    float* __restrict__ out,
    int niter)
{
    constexpr int LOGC = (COUT == 64) ? 6 : 5;
    constexpr int GPW  = 64 / COUT;
    constexpr int GPB  = 4 * GPW;
    constexpr int C4   = CIN / 4;
    constexpr int SJ   = (K_ + 1) * CIN;
    constexpr int HTS  = COUT + 1;
    constexpr int HTN  = PHA ? 1 : (K_ * HTS);
    constexpr int PN   = PHA ? 1 : (K_ * K_);
    constexpr int KQN  = PHA ? 1 : (2 * K_);
    constexpr int SCN  = PHA ? 1 : K_;
    constexpr int PARTN= (!PHA && COUT == 64) ? 64 : 1;
    constexpr int WKQN = PHA ? 1 : (2 * COUT);

    const int tid  = threadIdx.x;
    const int wave = tid >> 6;
    const int lane = tid & 63;
    const int lo   = lane & (COUT - 1);
    const int grp  = lane >> LOGC;
    const int gidx = wave * GPW + grp;

    __shared__ __align__(16) float sj_s[GPB][SJ];
    __shared__ __align__(16) float hT_s[GPB][HTN];
    __shared__ __align__(16) float p_s[GPB][PN];
    __shared__ __align__(16) float kqv_s[GPB][KQN];
    __shared__ __align__(16) float rden_s[GPB][SCN];
    __shared__ __align__(16) float scal_s[GPB][SCN];
    __shared__ __align__(16) float part_s[GPB][PARTN];
    __shared__ __align__(16) float wkq_s[WKQN];

    float Wr[CIN], Ad[CIN];
#pragma unroll
    for (int c = 0; c < CIN; ++c) {
        float wl = W[lo * (2*CIN) + c];
        float wr = W[lo * (2*CIN) + CIN + c];
        Wr[c] = wr; Ad[c] = wl - wr;
    }
    const float b_s = bias[lo];

    float a_s = 0.f, c_s = 0.f;
    if constexpr (!PHA) {
        a_s = acoef[lo]; c_s = ccoef[lo];
        if (tid < COUT)            wkq_s[tid] = wk[tid];
        else if (tid < 2*COUT)     wkq_s[tid] = wq[tid - COUT];
    }
    __syncthreads();

    double lsum = 0.0, lsq = 0.0;
    const int g0      = blockIdx.x * GPB + gidx;
    const int gstride = gridDim.x * GPB;

    for (int it = 0; it < niter; ++it) {
        const int n = g0 + it * gstride;

        {
            const float4* xs  = (const float4*)x;
            float4*       sj4 = (float4*)sj_s[gidx];
            constexpr int TOT4 = (K_ + 1) * C4;
#pragma unroll
            for (int e0 = 0; e0 < TOT4; e0 += COUT) {
                int e = e0 + lo;
                if (e < TOT4) {
                    int r = e / C4;
                    int c = e - r * C4;
                    int row = (r < K_) ? (int)idx[n * K_ + r] : n;
                    sj4[e] = xs[row * C4 + c];
                }
            }
        }
        if constexpr (!PHA) {
            if (lo < K_) {
                float dis = sqrtf(d2[n * K_ + lo]);
                float e = __expf(-dis);
                scal_s[gidx][lo] = 2.0f * e / (1.0f + e);
            }
        }
        __syncthreads();

        const float* sj = sj_s[gidx];
        float t0 = b_s;
#pragma unroll
        for (int c = 0; c < C4; ++c) {
            float4 v = ((const float4*)(sj + K_ * CIN))[c];
            t0 = fmaf(Ad[4*c  ], v.x, t0);
            t0 = fmaf(Ad[4*c+1], v.y, t0);
            t0 = fmaf(Ad[4*c+2], v.z, t0);
            t0 = fmaf(Ad[4*c+3], v.w, t0);
        }
        float hn[K_];
#pragma unroll
        for (int k = 0; k < K_; ++k) {
            float acc = t0;
            const float4* xr = (const float4*)(sj + k * CIN);
#pragma unroll
            for (int c = 0; c < C4; ++c) {
                float4 v = xr[c];
                acc = fmaf(Wr[4*c  ], v.x, acc);
                acc = fmaf(Wr[4*c+1], v.y, acc);
                acc = fmaf(Wr[4*c+2], v.z, acc);
                acc = fmaf(Wr[4*c+3], v.w, acc);
            }
            float h = fmaxf(acc, 0.f);
            if constexpr (PHA) {
                double hd = (double)h;
                lsum += hd;
                lsq  = fma(hd, hd, lsq);
            } else {
                hn[k] = fmaf(a_s, h, c_s);
            }
        }

        if constexpr (!PHA) {
            float* hT = hT_s[gidx];
#pragma unroll
            for (int k = 0; k < K_; ++k) hT[k * HTS + lo] = hn[k];
            __syncthreads();

            const int kk   = lo & 15;
            const int role = lo >> 4;
            float av = 0.f;
            const float* hrow = hT + kk * HTS;
            int obase; const float* wv;
            if constexpr (COUT == 64) { obase = (role & 1) * 32; wv = wkq_s + ((role >> 1) ? COUT : 0); }
            else                      { obase = 0;               wv = wkq_s + (role ? COUT : 0); }
#pragma unroll
            for (int j = 0; j < 32; ++j)
                av = fmaf(hrow[obase + j], wv[obase + j], av);
            if constexpr (COUT == 64) {
                part_s[gidx][lo] = av;
                __syncthreads();
                if (lo < 16)      kqv_s[gidx][lo] = part_s[gidx][lo]      + part_s[gidx][lo + 16];
                else if (lo < 32) kqv_s[gidx][lo] = part_s[gidx][lo + 16] + part_s[gidx][lo + 32];
            } else {
                kqv_s[gidx][lo] = av;
            }
            __syncthreads();

            if (lo < K_) {
                const int qq = lo;
                const float qv = kqv_s[gidx][K_ + qq];
                float m = -__builtin_huge_valf();
#pragma unroll
                for (int k = 0; k < K_; ++k) m = fmaxf(m, kqv_s[gidx][k] * qv);
                float den = 0.f;
#pragma unroll
                for (int k = 0; k < K_; ++k) {
                    float e = __expf(kqv_s[gidx][k] * qv - m);
                    den += e;
                    p_s[gidx][k * K_ + qq] = e;
                }
                rden_s[gidx][qq] = 1.0f / den;
            }
            __syncthreads();

            float hq[K_];
#pragma unroll
            for (int qq = 0; qq < K_; ++qq) hq[qq] = 0.f;
#pragma unroll
            for (int k = 0; k < K_; ++k) {
                const float hnk = hn[k];
                const float4* p4 = (const float4*)(p_s[gidx] + k * K_);
#pragma unroll
                for (int j = 0; j < 4; ++j) {
                    float4 v = p4[j];
                    hq[4*j  ] = fmaf(hnk, v.x, hq[4*j  ]);
                    hq[4*j+1] = fmaf(hnk, v.y, hq[4*j+1]);
                    hq[4*j+2] = fmaf(hnk, v.z, hq[4*j+2]);
                    hq[4*j+3] = fmaf(hnk, v.w, hq[4*j+3]);
                }
            }
            float res = -__builtin_huge_valf();
#pragma unroll
            for (int j = 0; j < 4; ++j) {
                float4 sc = ((const float4*)scal_s[gidx])[j];
                float4 rd = ((const float4*)rden_s[gidx])[j];
                res = fmaxf(res, sc.x * (hq[4*j  ] * rd.x));
                res = fmaxf(res, sc.y * (hq[4*j+1] * rd.y));
                res = fmaxf(res, sc.z * (hq[4*j+2] * rd.z));
                res = fmaxf(res, sc.w * (hq[4*j+3] * rd.w));
            }
            out[n * COUT + lo] = res;
            __syncthreads();
        } else {
            __syncthreads();
        }
    }

    if constexpr (PHA) {
        if constexpr (COUT == 32) {
            lsum += shfl_xor_dbl(lsum, 32);
            lsq  += shfl_xor_dbl(lsq, 32);
        }
        __shared__ double redS[4][COUT];
        __shared__ double redQ[4][COUT];
        if (lane < COUT) { redS[wave][lane] = lsum; redQ[wave][lane] = lsq; }
        __syncthreads();
        if (tid < COUT) {
            double ss = redS[0][tid] + redS[1][tid] + redS[2][tid] + redS[3][tid];
            double qq = redQ[0][tid] + redQ[1][tid] + redQ[2][tid] + redQ[3][tid];
            atomicAdd(&gsum[tid], ss);
            atomicAdd(&gsumsq[tid], qq);
        }
    }
}

__global__ void finalize_kernel(const double* __restrict__ gsum, const double* __restrict__ gsumsq,
                                const float* __restrict__ gamma, const float* __restrict__ beta,
                                float* __restrict__ a, float* __restrict__ c, int cout)
{
    int o = threadIdx.x;
    if (o < cout) {
        const double inv = 1.0 / ((double)N_ * (double)K_);
        double mu  = gsum[o] * inv;
        double var = gsumsq[o] * inv - mu * mu;
        double rs  = 1.0 / sqrt(var + (double)EPS_);
        double av  = rs * (double)gamma[o];
        a[o] = (float)av;
        c[o] = (float)((double)beta[o] - mu * av);
    }
}

__global__ __launch_bounds__(256) void copy_vc(const float4* __restrict__ src,
                                               float4* __restrict__ dst) {
    int i = blockIdx.x * 256 + threadIdx.x;
    dst[i] = src[i];
}

extern "C" void kernel_launch(void* const* d_in, const int* in_sizes, int n_in,
                              void* d_out, int out_size, void* d_ws, size_t ws_size,
                              hipStream_t stream)
{
    const float* pillar = (const float*)d_in[0];
    const float* vc     = (const float*)d_in[1];
    const float* W0  = (const float*)d_in[2];
    const float* b0  = (const float*)d_in[3];
    const float* g0  = (const float*)d_in[4];
    const float* be0 = (const float*)d_in[5];
    const float* wk0 = (const float*)d_in[6];
    const float* wq0 = (const float*)d_in[7];
    const float* W1  = (const float*)d_in[8];
    const float* b1  = (const float*)d_in[9];
    const float* g1  = (const float*)d_in[10];
    const float* be1 = (const float*)d_in[11];
    const float* wk1 = (const float*)d_in[12];
    const float* wq1 = (const float*)d_in[13];

    // ---- workspace (< 16 MiB total) ----
    char* ws = (char*)d_ws;
    double* dsum = (double*)ws;                              // 2 KB @ 0
    double *s0 = dsum, *sq0 = dsum + 64, *s1 = dsum + 128, *sq1 = dsum + 192;
    float* coef = (float*)(ws + 4096);                       // 1 KB @ 4K
    float *a0 = coef, *c0 = coef + 64, *a1 = coef + 128, *c1 = coef + 192;
    unsigned short* idx = (unsigned short*)(ws + 8192);      // 2 MB
    float* d2  = (float*)(ws + 8192 + (size_t)N_*K_*2);      // 4 MB
    float* x1  = (float*)(ws + 8192 + (size_t)N_*K_*6);      // 8 MB
    size_t base2 = 8192 + (size_t)N_*K_*6 + (size_t)N_*32*4; // = 14 MB + 8 KB
    float4* pos4s = (float4*)(ws + base2);                   // 1 MB
    int* counts   = (int*)(ws + base2 + (1u<<20));           // 32 KB
    int* cursors  = counts + B_*NBK;                         // 32 KB
    int* off      = cursors + B_*NBK;                        // 8*1025*4
    int* xminI    = off + B_*(NBK+1);                        // 32 KB
    int* xmaxI    = xminI + B_*NBK;                          // 32 KB
    float* xlub   = (float*)(xmaxI + B_*NBK);                // 32 KB
    float* xglb   = xlub + B_*NBK;                           // 32 KB

    float* xout = (float*)d_out;
    float* vout = xout + (size_t)N_ * 64;

    hipMemsetAsync(dsum, 0, 2048, stream);
    init_bins<<<B_*NBK/256, 256, 0, stream>>>(counts, cursors, xminI, xmaxI);
    count_kernel<<<N_/256, 256, 0, stream>>>(vc, counts, xminI, xmaxI);
    scan_kernel<<<B_, NBK, 0, stream>>>(counts, xminI, xmaxI, off, xlub, xglb);
    scatter_kernel<<<N_/256, 256, 0, stream>>>(vc, off, cursors, pos4s);
    knn3_kernel<<<N_/256, 256, 0, stream>>>(pos4s, xlub, xglb, idx, d2);

    edge_kernel<4,32,true ><<<1024, 256, 0, stream>>>(pillar, idx, d2, W0, b0, wk0, wq0,
                                                      nullptr, nullptr, s0, sq0, nullptr, 8);
    finalize_kernel<<<1, 64, 0, stream>>>(s0, sq0, g0, be0, a0, c0, 32);
    edge_kernel<4,32,false><<<1024, 256, 0, stream>>>(pillar, idx, d2, W0, b0, wk0, wq0,
                                                      a0, c0, nullptr, nullptr, x1, 8);

    edge_kernel<32,64,true ><<<2048, 256, 0, stream>>>(x1, idx, d2, W1, b1, wk1, wq1,
                                                       nullptr, nullptr, s1, sq1, nullptr, 8);
    finalize_kernel<<<1, 64, 0, stream>>>(s1, sq1, g1, be1, a1, c1, 64);
    edge_kernel<32,64,false><<<2048, 256, 0, stream>>>(x1, idx, d2, W1, b1, wk1, wq1,
                                                       a1, c1, nullptr, nullptr, xout, 8);

    copy_vc<<<256, 256, 0, stream>>>((const float4*)vc, (float4*)vout);
}